// Round 13
// baseline (112.293 us; speedup 1.0000x reference)
//
#include <hip/hip_runtime.h>
#include <math.h>

typedef __attribute__((ext_vector_type(8))) short short8;
typedef __attribute__((ext_vector_type(4))) float f32x4;
typedef __attribute__((ext_vector_type(16))) float f32x16;

#define BDIM 2
#define T_LEN 2048
#define CDIM 1024
#define NH 16
#define DHEAD 64
#define M_ROWS (BDIM * T_LEN)            // 4096
#define NX (M_ROWS * CDIM)               // 4194304
#define NW (CDIM * CDIM)                 // 1048576

#define KVB 64
#define QSCL 0.045084220f                // C^-0.5 * log2(e), folded into Wq

__device__ inline unsigned short f2bf(float f) {
    union { float f; unsigned u; } v; v.f = f;
    unsigned r = v.u + 0x7fff + ((v.u >> 16) & 1);   // RNE
    return (unsigned short)(r >> 16);
}

__device__ __forceinline__ void gload16(const unsigned short* g, unsigned short* l) {
    __builtin_amdgcn_global_load_lds(
        (const __attribute__((address_space(1))) void*)g,
        (__attribute__((address_space(3))) void*)l, 16, 0, 0);
}

// ---------------- Kernel 0: fp32 -> bf16 convert (x, Wq*QSCL, Wk, Wv) ----------------
__global__ __launch_bounds__(256) void conv_bf16(
    const float* __restrict__ x, const float* __restrict__ wq,
    const float* __restrict__ wk, const float* __restrict__ wv,
    unsigned short* __restrict__ dst)
{
    int id = blockIdx.x * 256 + threadIdx.x;        // 16B-out chunk id
    const float* s;
    float scl = 1.0f;
    if (id < NX / 8) s = x + (size_t)id * 8;
    else {
        int r = id - NX / 8;
        int wsel = r >> 17;                          // NW/8 = 131072 = 2^17
        int off = r & 131071;
        const float* w = (wsel == 0) ? wq : (wsel == 1) ? wk : wv;
        if (wsel == 0) scl = QSCL;                   // pre-scale Q via Wq
        s = w + (size_t)off * 8;
    }
    float4 a = ((const float4*)s)[0];
    float4 b = ((const float4*)s)[1];
    union { unsigned short u[8]; short8 v; } o;
    o.u[0] = f2bf(a.x * scl); o.u[1] = f2bf(a.y * scl); o.u[2] = f2bf(a.z * scl); o.u[3] = f2bf(a.w * scl);
    o.u[4] = f2bf(b.x * scl); o.u[5] = f2bf(b.y * scl); o.u[6] = f2bf(b.z * scl); o.u[7] = f2bf(b.w * scl);
    *(short8*)(dst + (size_t)id * 8) = o.v;
}

// ---------------- Kernel 1: 8-phase 256x256 bf16 QKV GEMM, BK=64 ----------------
// Q,K -> [b][h][t][d]; V -> transposed [b][h][d][t].
// 8 waves (2M x 4N), per-wave C = 128x64. LDS: 2 bufs x {A,B} x 2 half-tiles(128x64).
// Raw s_barrier (no forced drain); vmcnt(0) only at phases 4/8 (>=3 phases hiding).
__global__ __launch_bounds__(512) void qkv_gemm8(
    const unsigned short* __restrict__ xb, const unsigned short* __restrict__ wb,
    unsigned short* __restrict__ qkv)
{
    __shared__ __align__(16) unsigned short sh[65536];   // 128 KB
    // A[buf][h] slot at (buf*2+h)*8192 shorts; B[buf][h] at 32768 + (buf*2+h)*8192
    const int z = blockIdx.z;
    const int m0 = blockIdx.x * 256;
    const int n0 = blockIdx.y * 256;
    const int tid = threadIdx.x;
    const int l = tid & 63, w = tid >> 6;
    const int li = l & 15, g4 = l >> 4;
    const int wr = w >> 2, wc = w & 3;
    const unsigned short* wsrc = wb + (size_t)z * NW;

    f32x4 acc[8][4] = {};

    // stage all 4 half-tiles of K-tile kt into buf (8 gload16/thread)
    auto STG4 = [&](int buf, int kt) {
        #pragma unroll
        for (int hh = 0; hh < 2; ++hh)
            #pragma unroll
            for (int s = 0; s < 2; ++s) {
                int c = s * 512 + w * 64 + l;            // chunk 0..1023
                int row = c >> 3, col8 = c & 7;
                int sw = col8 ^ (row & 7);
                int db = (s * 512 + w * 64) * 8;         // wave-uniform LDS base (shorts)
                gload16(xb + (size_t)(m0 + hh * 128 + row) * CDIM + kt * 64 + sw * 8,
                        &sh[(buf * 2 + hh) * 8192 + db]);
                gload16(wsrc + (size_t)(n0 + hh * 128 + row) * CDIM + kt * 64 + sw * 8,
                        &sh[32768 + (buf * 2 + hh) * 8192 + db]);
            }
    };
    auto RD_A = [&](int buf, int qm, int fm, int kk) -> short8 {
        int rloc = qm * 64 + fm * 16 + li;
        int byte = rloc * 128 + kk * 64 + g4 * 16;
        return *(const short8*)((const char*)&sh[(buf * 2 + wr) * 8192] + (byte ^ ((rloc & 7) << 4)));
    };
    auto RD_B = [&](int buf, int qn, int fn, int kk) -> short8 {
        int rloc = (wc & 1) * 64 + qn * 32 + fn * 16 + li;
        int byte = rloc * 128 + kk * 64 + g4 * 16;
        return *(const short8*)((const char*)&sh[32768 + (buf * 2 + (wc >> 1)) * 8192] + (byte ^ ((rloc & 7) << 4)));
    };

#define PHASE(buf_, qm_, qn_, WAITV_, ...)                                             \
    {                                                                                  \
        short8 pa[4][2], pb[2][2];                                                     \
        _Pragma("unroll")                                                              \
        for (int fm = 0; fm < 4; ++fm) {                                               \
            pa[fm][0] = RD_A(buf_, qm_, fm, 0); pa[fm][1] = RD_A(buf_, qm_, fm, 1);    \
        }                                                                              \
        _Pragma("unroll")                                                              \
        for (int fn = 0; fn < 2; ++fn) {                                               \
            pb[fn][0] = RD_B(buf_, qn_, fn, 0); pb[fn][1] = RD_B(buf_, qn_, fn, 1);    \
        }                                                                              \
        __VA_ARGS__;                                                                   \
        __builtin_amdgcn_s_barrier();                                                  \
        __builtin_amdgcn_s_setprio(1);                                                 \
        _Pragma("unroll")                                                              \
        for (int fm = 0; fm < 4; ++fm)                                                 \
            _Pragma("unroll")                                                          \
            for (int fn = 0; fn < 2; ++fn) {                                           \
                acc[(qm_)*4 + fm][(qn_)*2 + fn] = __builtin_amdgcn_mfma_f32_16x16x32_bf16( \
                    pa[fm][0], pb[fn][0], acc[(qm_)*4 + fm][(qn_)*2 + fn], 0, 0, 0);   \
                acc[(qm_)*4 + fm][(qn_)*2 + fn] = __builtin_amdgcn_mfma_f32_16x16x32_bf16( \
                    pa[fm][1], pb[fn][1], acc[(qm_)*4 + fm][(qn_)*2 + fn], 0, 0, 0);   \
            }                                                                          \
        __builtin_amdgcn_s_setprio(0);                                                 \
        if (WAITV_) asm volatile("s_waitcnt vmcnt(0)" ::: "memory");                   \
        __builtin_amdgcn_s_barrier();                                                  \
    }

    // prologue: K-tile 0 -> buf0
    STG4(0, 0);
    asm volatile("s_waitcnt vmcnt(0)" ::: "memory");
    __builtin_amdgcn_s_barrier();

    for (int u = 0; u < 8; ++u) {
        const int kt1 = 2 * u + 1;
        const int kt2 = 2 * u + 2;
        const bool st = (u < 7);
        // group 1: compute K-tile 2u from buf0; ph1 stages buf1 <- kt1
        PHASE(0, 0, 0, false, STG4(1, kt1))
        PHASE(0, 0, 1, false, )
        PHASE(0, 1, 0, false, )
        PHASE(0, 1, 1, true, )
        // group 2: compute K-tile 2u+1 from buf1; ph5 stages buf0 <- kt2
        PHASE(1, 0, 0, false, if (st) STG4(0, kt2))
        PHASE(1, 0, 1, false, )
        PHASE(1, 1, 0, false, )
        PHASE(1, 1, 1, st, )
    }
#undef PHASE

    if (z != 2) {
        unsigned short* outp = qkv + (size_t)z * NX;
        #pragma unroll
        for (int am = 0; am < 8; ++am)
            #pragma unroll
            for (int an = 0; an < 4; ++an)
                #pragma unroll
                for (int r = 0; r < 4; ++r) {
                    int m = m0 + wr * 128 + am * 16 + g4 * 4 + r;
                    int n = n0 + wc * 64 + an * 16 + li;
                    int b = m >> 11, t = m & 2047;
                    int h = n >> 6, dd = n & 63;
                    outp[((size_t)(b * NH + h) << 17) + ((size_t)t << 6) + dd] = f2bf(acc[am][an][r]);
                }
    } else {
        // two-pass 256x256 transpose through LDS -> V^T[bh][dd][t]
        unsigned short (*T)[136] = (unsigned short(*)[136])sh;
        int b = m0 >> 11;
        int t0 = m0 & 2047;
        unsigned short* vt = qkv + 2 * (size_t)NX;
        #pragma unroll
        for (int mh = 0; mh < 2; ++mh) {
            __syncthreads();
            if (wr == mh) {
                #pragma unroll
                for (int am = 0; am < 8; ++am)
                    #pragma unroll
                    for (int an = 0; an < 4; ++an)
                        #pragma unroll
                        for (int r = 0; r < 4; ++r) {
                            int ml = am * 16 + g4 * 4 + r;         // 0..127
                            int nl = wc * 64 + an * 16 + li;       // 0..255
                            T[nl][ml] = f2bf(acc[am][an][r]);
                        }
            }
            __syncthreads();
            int row = tid >> 1;                                    // 0..255
            int ng = n0 + row;
            int h = ng >> 6, dd = ng & 63;
            unsigned short* dstr = vt + ((size_t)(b * NH + h) * 64 + dd) * T_LEN + t0 + mh * 128;
            #pragma unroll
            for (int s = 0; s < 8; ++s) {
                int col = (tid & 1) * 64 + s * 8;                  // 0..127
                *(short8*)(dstr + col) = *(const short8*)&T[row][col];
            }
        }
    }
}

// ---------------- Kernel 2: causal flash attention (r12 verbatim, 61us) ----------------
__global__ __launch_bounds__(512, 4) void attn(
    const unsigned short* __restrict__ qkv, float* __restrict__ out)
{
    __shared__ __align__(16) unsigned short KV[2][2][2][4096];

    const int id = blockIdx.x;
    const int half = id >> 8;
    const int rr = id & 255;
    const int tI = rr >> 5;                           // 0..7
    const int bx = half ? tI : (15 - tI);             // pair (15-tI, tI): 17 units/CU
    const int rb = rr & 31;
    const int bh = (rb & 7) * 4 + (rb >> 3);          // XCD spread; pair shares bh
    const int b = bh >> 4, h = bh & 15;
    const int q0 = bx * 128;
    const int tid = threadIdx.x;
    const int l = tid & 63, w = tid >> 6;             // w: 0..7
    const int hf = w >> 2, chunk = w & 3;
    const int q31 = l & 31, hi = l >> 5;

    const unsigned short* qp = qkv + (size_t)bh * (T_LEN * DHEAD);
    const unsigned short* kp = qkv + (size_t)NX + (size_t)bh * (T_LEN * DHEAD);
    const unsigned short* vp = qkv + 2 * (size_t)NX + (size_t)bh * (T_LEN * DHEAD); // [dd][t]

    const int q0w = q0 + chunk * 32;
    const int qg = q0w + q31;

    short8 aq[4];
    #pragma unroll
    for (int ks = 0; ks < 4; ++ks)
        aq[ks] = *(const short8*)(qp + (size_t)qg * DHEAD + ks * 16 + hi * 8);

    float m_run = -INFINITY, l_run = 0.f;
    f32x16 acc_o[2] = {};

    const int nIt = bx + 1;
    const int Tbase = hf * nIt;
    const int myNt = 2 * bx + (chunk >> 1) + 1;

    auto STAGE = [&](int tile, int bf) {
        const int kv0 = tile * KVB;
        #pragma unroll
        for (int s = 0; s < 2; ++s) {
            int c = (chunk * 2 + s) * 64 + l;
            int row = c >> 3, wc_ = c & 7;
            int sw = wc_ ^ (row & 7);
            gload16(kp + (size_t)(kv0 + row) * DHEAD + sw * 8, &KV[hf][bf][0][(chunk * 2 + s) * 512]);
            gload16(vp + (size_t)row * T_LEN + kv0 + sw * 8, &KV[hf][bf][1][(chunk * 2 + s) * 512]);
        }
    };

    STAGE(Tbase, 0);
    asm volatile("s_waitcnt vmcnt(0)" ::: "memory");
    __syncthreads();

    for (int i = 0; i < nIt; ++i) {
        const int cur = i & 1;
        if (i + 1 < nIt) STAGE(Tbase + i + 1, cur ^ 1);
        const int Ti = Tbase + i;
        const int kv0 = Ti * KVB;

        if (Ti < myNt) {
            const char* Kbase = (const char*)&KV[hf][cur][0][0];
            const char* Vbase = (const char*)&KV[hf][cur][1][0];

            f32x16 sacc[2] = {};
            __builtin_amdgcn_s_setprio(1);
            #pragma unroll
            for (int ks = 0; ks < 4; ++ks) {
                #pragma unroll
                for (int nb = 0; nb < 2; ++nb) {
                    int row = 32 * nb + q31;
                    int lin = row * 128 + ks * 32 + hi * 16;
                    short8 ak = *(const short8*)(Kbase + (lin ^ ((l & 7) << 4)));
                    sacc[nb] = __builtin_amdgcn_mfma_f32_32x32x16_bf16(ak, aq[ks], sacc[nb], 0, 0, 0);
                }
            }
            __builtin_amdgcn_s_setprio(0);

            const bool domask = (kv0 + KVB - 1 > q0w);
            if (domask) {
                #pragma unroll
                for (int nb = 0; nb < 2; ++nb)
                    #pragma unroll
                    for (int r = 0; r < 16; ++r) {
                        int kvg = kv0 + 32 * nb + (r & 3) + 8 * (r >> 2) + 4 * hi;
                        if (kvg > qg) sacc[nb][r] = -INFINITY;
                    }
            }
            float m16[16];
            #pragma unroll
            for (int r = 0; r < 16; ++r) m16[r] = fmaxf(sacc[0][r], sacc[1][r]);
            #pragma unroll
            for (int st = 8; st >= 1; st >>= 1)
                #pragma unroll
                for (int r2 = 0; r2 < 8; ++r2)
                    if (r2 < st) m16[r2] = fmaxf(m16[r2], m16[r2 + st]);
            float mloc = fmaxf(m16[0], __shfl_xor(m16[0], 32));

            bool upd = mloc > m_run + 8.0f;
            if (__any(upd)) {
                float mn = fmaxf(m_run, mloc);
                float c = exp2f(m_run - mn);
                l_run *= c;
                #pragma unroll
                for (int nb2 = 0; nb2 < 2; ++nb2)
                    #pragma unroll
                    for (int r = 0; r < 16; ++r)
                        acc_o[nb2][r] *= c;
                m_run = mn;
            }
            float ps[16];
            #pragma unroll
            for (int r = 0; r < 16; ++r) {
                float p0 = exp2f(sacc[0][r] - m_run);
                float p1 = exp2f(sacc[1][r] - m_run);
                sacc[0][r] = p0; sacc[1][r] = p1;
                ps[r] = p0 + p1;
            }
            #pragma unroll
            for (int st = 8; st >= 1; st >>= 1)
                #pragma unroll
                for (int r2 = 0; r2 < 8; ++r2)
                    if (r2 < st) ps[r2] += ps[r2 + st];
            l_run += ps[0] + __shfl_xor(ps[0], 32);

            unsigned dw[16];
            #pragma unroll
            for (int u = 0; u < 16; ++u) {
                float lo = sacc[u >> 3][(2 * u) & 15];
                float hif = sacc[u >> 3][((2 * u) & 15) + 1];
                asm("v_cvt_pk_bf16_f32 %0, %1, %2" : "=v"(dw[u]) : "v"(lo), "v"(hif));
            }

            __builtin_amdgcn_s_setprio(1);
            #pragma unroll
            for (int ks = 0; ks < 4; ++ks) {
                unsigned a0 = dw[4 * ks],     b0 = dw[4 * ks + 2];
                unsigned a1 = dw[4 * ks + 1], b1 = dw[4 * ks + 3];
                asm("v_permlane32_swap_b32 %0, %1" : "+v"(a0), "+v"(b0));
                asm("v_permlane32_swap_b32 %0, %1" : "+v"(a1), "+v"(b1));
                union { unsigned u[4]; short8 v; } pb;
                pb.u[0] = a0; pb.u[1] = a1; pb.u[2] = b0; pb.u[3] = b1;
                #pragma unroll
                for (int nb2 = 0; nb2 < 2; ++nb2) {
                    int row = 32 * nb2 + q31;
                    int lin = row * 128 + ks * 32 + hi * 16;
                    short8 av = *(const short8*)(Vbase + (lin ^ ((l & 7) << 4)));
                    acc_o[nb2] = __builtin_amdgcn_mfma_f32_32x32x16_bf16(av, pb.v, acc_o[nb2], 0, 0, 0);
                }
            }
            __builtin_amdgcn_s_setprio(0);
        }
        asm volatile("s_waitcnt vmcnt(0)" ::: "memory");
        __syncthreads();
    }

    float* MB = (float*)&KV[0][0][0][0];
    float* slot = MB + (chunk * 64 + l) * 34;
    if (hf) {
        #pragma unroll
        for (int nb2 = 0; nb2 < 2; ++nb2)
            #pragma unroll
            for (int r = 0; r < 16; ++r) slot[nb2 * 16 + r] = acc_o[nb2][r];
        slot[32] = m_run; slot[33] = l_run;
    }
    __syncthreads();
    if (!hf) {
        float mB = slot[32], lB = slot[33];
        float m = fmaxf(m_run, mB);
        float cA = exp2f(m_run - m), cB = exp2f(mB - m);
        float inv = 1.0f / (l_run * cA + lB * cB);
        float* ob = out + ((size_t)(b * T_LEN + qg)) * CDIM + h * DHEAD;
        #pragma unroll
        for (int nb2 = 0; nb2 < 2; ++nb2)
            #pragma unroll
            for (int r = 0; r < 16; ++r) {
                int dd = 32 * nb2 + (r & 3) + 8 * (r >> 2) + 4 * hi;
                ob[dd] = (acc_o[nb2][r] * cA + slot[nb2 * 16 + r] * cB) * inv;
            }
    }
}

extern "C" void kernel_launch(void* const* d_in, const int* in_sizes, int n_in,
                              void* d_out, int out_size, void* d_ws, size_t ws_size,
                              hipStream_t stream) {
    const float* x  = (const float*)d_in[0];
    const float* Wq = (const float*)d_in[1];
    const float* Wk = (const float*)d_in[2];
    const float* Wv = (const float*)d_in[3];
    float* out = (float*)d_out;

    unsigned short* xb = (unsigned short*)d_out;      // bf16 scratch in d_out (overwritten by attn)
    unsigned short* wb = xb + NX;
    unsigned short* qkv = (unsigned short*)d_ws;

    conv_bf16<<<dim3((NX / 8 + 3 * NW / 8) / 256), dim3(256), 0, stream>>>(x, Wq, Wk, Wv, xb);
    qkv_gemm8<<<dim3(M_ROWS / 256, CDIM / 256, 3), dim3(512), 0, stream>>>(xb, wb, qkv);
    attn<<<dim3(512), dim3(512), 0, stream>>>(qkv, out);
}

// Round 14
// 102.120 us; speedup vs baseline: 1.0996x; 1.0996x over previous
//
#include <hip/hip_runtime.h>
#include <math.h>

typedef __attribute__((ext_vector_type(8))) short short8;
typedef __attribute__((ext_vector_type(4))) float f32x4;
typedef __attribute__((ext_vector_type(16))) float f32x16;

#define BDIM 2
#define T_LEN 2048
#define CDIM 1024
#define NH 16
#define DHEAD 64
#define M_ROWS (BDIM * T_LEN)            // 4096
#define NX (M_ROWS * CDIM)               // 4194304
#define NW (CDIM * CDIM)                 // 1048576

#define QSCL 0.045084220f                // C^-0.5 * log2(e), folded into Wq

__device__ inline unsigned short f2bf(float f) {
    union { float f; unsigned u; } v; v.f = f;
    unsigned r = v.u + 0x7fff + ((v.u >> 16) & 1);   // RNE
    return (unsigned short)(r >> 16);
}

__device__ __forceinline__ void gload16(const unsigned short* g, unsigned short* l) {
    __builtin_amdgcn_global_load_lds(
        (const __attribute__((address_space(1))) void*)g,
        (__attribute__((address_space(3))) void*)l, 16, 0, 0);
}

// ---------------- Kernel 0: fp32 -> bf16 convert (x, Wq*QSCL, Wk, Wv) ----------------
__global__ __launch_bounds__(256) void conv_bf16(
    const float* __restrict__ x, const float* __restrict__ wq,
    const float* __restrict__ wk, const float* __restrict__ wv,
    unsigned short* __restrict__ dst)
{
    int id = blockIdx.x * 256 + threadIdx.x;        // 16B-out chunk id
    const float* s;
    float scl = 1.0f;
    if (id < NX / 8) s = x + (size_t)id * 8;
    else {
        int r = id - NX / 8;
        int wsel = r >> 17;                          // NW/8 = 131072 = 2^17
        int off = r & 131071;
        const float* w = (wsel == 0) ? wq : (wsel == 1) ? wk : wv;
        if (wsel == 0) scl = QSCL;                   // pre-scale Q via Wq
        s = w + (size_t)off * 8;
    }
    float4 a = ((const float4*)s)[0];
    float4 b = ((const float4*)s)[1];
    union { unsigned short u[8]; short8 v; } o;
    o.u[0] = f2bf(a.x * scl); o.u[1] = f2bf(a.y * scl); o.u[2] = f2bf(a.z * scl); o.u[3] = f2bf(a.w * scl);
    o.u[4] = f2bf(b.x * scl); o.u[5] = f2bf(b.y * scl); o.u[6] = f2bf(b.z * scl); o.u[7] = f2bf(b.w * scl);
    *(short8*)(dst + (size_t)id * 8) = o.v;
}

// ---------------- Kernel 1: bf16 QKV GEMM, 128x128 tile, BK=64 (round-12 proven) ----------------
__global__ __launch_bounds__(256) void qkv_gemm_f(
    const unsigned short* __restrict__ xb, const unsigned short* __restrict__ wb,
    unsigned short* __restrict__ qkv)
{
    __shared__ unsigned short sh[17408];
    unsigned short* A = sh;
    unsigned short* Bt = sh + 8192;
    const int z = blockIdx.z;
    const int m0 = blockIdx.x * 128;
    const int n0 = blockIdx.y * 128;
    const int tid = threadIdx.x;
    const int l = tid & 63, w = tid >> 6;
    const int li = l & 15, g4 = l >> 4;
    const int wr = w >> 1, wc = w & 1;

    const unsigned short* wsrc = wb + (size_t)z * NW;
    f32x4 acc[4][4] = {};

    for (int k0 = 0; k0 < CDIM; k0 += 64) {
        __syncthreads();
        #pragma unroll
        for (int s = 0; s < 4; ++s) {
            int c = w * 256 + s * 64 + l;
            int row = c >> 3, wcol = c & 7;
            int sw = wcol ^ (row & 7);
            gload16(xb + (size_t)(m0 + row) * CDIM + k0 + sw * 8, A + (w * 256 + s * 64) * 8);
            gload16(wsrc + (size_t)(n0 + row) * CDIM + k0 + sw * 8, Bt + (w * 256 + s * 64) * 8);
        }
        asm volatile("s_waitcnt vmcnt(0)" ::: "memory");
        __syncthreads();
        __builtin_amdgcn_s_setprio(1);
        #pragma unroll
        for (int ks = 0; ks < 2; ++ks) {
            short8 af[4], bf[4];
            #pragma unroll
            for (int fm = 0; fm < 4; ++fm) {
                int row = wr * 64 + fm * 16 + li;
                int lin = row * 128 + ks * 64 + g4 * 16;
                af[fm] = *(const short8*)((const char*)A + (lin ^ ((row & 7) << 4)));
            }
            #pragma unroll
            for (int fn = 0; fn < 4; ++fn) {
                int row = wc * 64 + fn * 16 + li;
                int lin = row * 128 + ks * 64 + g4 * 16;
                bf[fn] = *(const short8*)((const char*)Bt + (lin ^ ((row & 7) << 4)));
            }
            #pragma unroll
            for (int fm = 0; fm < 4; ++fm)
                #pragma unroll
                for (int fn = 0; fn < 4; ++fn)
                    acc[fm][fn] = __builtin_amdgcn_mfma_f32_16x16x32_bf16(af[fm], bf[fn], acc[fm][fn], 0, 0, 0);
        }
        __builtin_amdgcn_s_setprio(0);
    }
    __syncthreads();

    if (z != 2) {
        unsigned short* outp = qkv + (size_t)z * NX;
        #pragma unroll
        for (int fm = 0; fm < 4; ++fm)
            #pragma unroll
            for (int fn = 0; fn < 4; ++fn)
                #pragma unroll
                for (int r = 0; r < 4; ++r) {
                    int m = m0 + wr * 64 + fm * 16 + g4 * 4 + r;
                    int n = n0 + wc * 64 + fn * 16 + li;
                    int b = m >> 11, t = m & 2047;
                    int h = n >> 6, dd = n & 63;
                    outp[((size_t)(b * NH + h) << 17) + ((size_t)t << 6) + dd] = f2bf(acc[fm][fn][r]);
                }
    } else {
        unsigned short (*T)[136] = (unsigned short(*)[136])sh;
        #pragma unroll
        for (int fm = 0; fm < 4; ++fm)
            #pragma unroll
            for (int fn = 0; fn < 4; ++fn)
                #pragma unroll
                for (int r = 0; r < 4; ++r) {
                    int ml = wr * 64 + fm * 16 + g4 * 4 + r;
                    int nl = wc * 64 + fn * 16 + li;
                    T[nl][ml] = f2bf(acc[fm][fn][r]);
                }
        __syncthreads();
        int b = m0 >> 11;
        int t0 = m0 & 2047;
        unsigned short* vt = qkv + 2 * (size_t)NX;
        #pragma unroll
        for (int s = 0; s < 8; ++s) {
            int row = tid >> 1;
            int col = ((tid & 1) * 8 + s) * 8;
            int ng = n0 + row;
            int h = ng >> 6, dd = ng & 63;
            *(short8*)(vt + ((size_t)(b * NH + h) * 64 + dd) * T_LEN + t0 + col)
                = *(const short8*)&T[row][col];
        }
    }
}

// ---------------- Kernel 2: causal flash attention, 128-row KV staging ----------------
// 8 waves: halves A/B split the 128-tile range [0, bx+1) -> longest chain 8 iters.
// Each staged 128-tile computed as two 64-sub-tiles (lean registers). 128 KB LDS.
__global__ __launch_bounds__(512, 2) void attn(
    const unsigned short* __restrict__ qkv, float* __restrict__ out)
{
    // [half][dbuf][K=0/V=1][8192 shorts = 16KB] -> 128 KB
    __shared__ __align__(16) unsigned short KV[2][2][2][8192];

    const int id = blockIdx.x;
    const int half = id >> 8;
    const int rr = id & 255;
    const int tI = rr >> 5;                           // 0..7
    const int bx = half ? tI : (15 - tI);             // sequential pair: 9 units/CU
    const int rb = rr & 31;
    const int bh = (rb & 7) * 4 + (rb >> 3);          // XCD spread
    const int b = bh >> 4, h = bh & 15;
    const int q0 = bx * 128;
    const int tid = threadIdx.x;
    const int l = tid & 63, w = tid >> 6;             // w: 0..7
    const int hf = w >> 2, chunk = w & 3;
    const int q31 = l & 31, hi = l >> 5;

    const unsigned short* qp = qkv + (size_t)bh * (T_LEN * DHEAD);
    const unsigned short* kp = qkv + (size_t)NX + (size_t)bh * (T_LEN * DHEAD);
    const unsigned short* vp = qkv + 2 * (size_t)NX + (size_t)bh * (T_LEN * DHEAD); // [dd][t]

    const int q0w = q0 + chunk * 32;
    const int qg = q0w + q31;

    short8 aq[4];
    #pragma unroll
    for (int ks = 0; ks < 4; ++ks)
        aq[ks] = *(const short8*)(qp + (size_t)qg * DHEAD + ks * 16 + hi * 8);

    float m_run = -INFINITY, l_run = 0.f;
    f32x16 acc_o[2] = {};

    const int T128 = bx + 1;                          // 128-row kv tiles for this q-block
    const int hA = (T128 + 1) >> 1;
    const int base = hf ? hA : 0;                     // my half's first 128-tile
    const int lim  = hf ? T128 : hA;                  // my half's end
    const int nIt  = hA;                              // loop count (A >= B)
    const int myNt64 = 2 * bx + (chunk >> 1) + 1;     // causal 64-tile limit for this chunk

    auto STAGE = [&](int j, int bf) {
        const int kv0 = j * 128;
        #pragma unroll
        for (int s = 0; s < 4; ++s) {
            int g = (chunk * 4 + s) * 64 + l;         // 16B chunk 0..1023
            int krow = g >> 3, kc = g & 7;
            int ksw = kc ^ (krow & 7);
            gload16(kp + (size_t)(kv0 + krow) * DHEAD + ksw * 8, &KV[hf][bf][0][(chunk * 4 + s) * 512]);
            int sub = g >> 9, cs = g & 511;           // V: two [64][64] sub-tiles
            int vrow = cs >> 3, vc = cs & 7;
            int vsw = vc ^ (vrow & 7);
            gload16(vp + (size_t)vrow * T_LEN + kv0 + sub * 64 + vsw * 8, &KV[hf][bf][1][(chunk * 4 + s) * 512]);
        }
    };

    if (base < lim) STAGE(base, 0);
    asm volatile("s_waitcnt vmcnt(0)" ::: "memory");
    __syncthreads();

    for (int i = 0; i < nIt; ++i) {
        const int cur = i & 1;
        const int myJ = base + i;
        if (myJ + 1 < lim) STAGE(myJ + 1, cur ^ 1);

        #pragma unroll
        for (int sub = 0; sub < 2; ++sub) {
            const int t64 = myJ * 2 + sub;
            if (myJ < lim && t64 < myNt64) {
                const char* Kbase = (const char*)&KV[hf][cur][0][0] + sub * 8192;
                const char* Vbase = (const char*)&KV[hf][cur][1][0] + sub * 8192;
                const int kv0 = t64 * 64;

                // ---- S^T = K Q^T ----
                f32x16 sacc[2] = {};
                __builtin_amdgcn_s_setprio(1);
                #pragma unroll
                for (int ks = 0; ks < 4; ++ks) {
                    #pragma unroll
                    for (int nb = 0; nb < 2; ++nb) {
                        int row = 32 * nb + q31;
                        int lin = row * 128 + ks * 32 + hi * 16;
                        short8 ak = *(const short8*)(Kbase + (lin ^ ((l & 7) << 4)));
                        sacc[nb] = __builtin_amdgcn_mfma_f32_32x32x16_bf16(ak, aq[ks], sacc[nb], 0, 0, 0);
                    }
                }
                __builtin_amdgcn_s_setprio(0);

                // ---- online softmax (exp2 domain) ----
                const bool domask = (kv0 + 63 > q0w);
                if (domask) {
                    #pragma unroll
                    for (int nb = 0; nb < 2; ++nb)
                        #pragma unroll
                        for (int r = 0; r < 16; ++r) {
                            int kvg = kv0 + 32 * nb + (r & 3) + 8 * (r >> 2) + 4 * hi;
                            if (kvg > qg) sacc[nb][r] = -INFINITY;
                        }
                }
                float m16[16];
                #pragma unroll
                for (int r = 0; r < 16; ++r) m16[r] = fmaxf(sacc[0][r], sacc[1][r]);
                #pragma unroll
                for (int st = 8; st >= 1; st >>= 1)
                    #pragma unroll
                    for (int r2 = 0; r2 < 8; ++r2)
                        if (r2 < st) m16[r2] = fmaxf(m16[r2], m16[r2 + st]);
                float mloc = fmaxf(m16[0], __shfl_xor(m16[0], 32));

                bool upd = mloc > m_run + 8.0f;       // defer-max
                if (__any(upd)) {
                    float mn = fmaxf(m_run, mloc);
                    float c = exp2f(m_run - mn);
                    l_run *= c;
                    #pragma unroll
                    for (int nb2 = 0; nb2 < 2; ++nb2)
                        #pragma unroll
                        for (int r = 0; r < 16; ++r)
                            acc_o[nb2][r] *= c;
                    m_run = mn;
                }
                float ps[16];
                #pragma unroll
                for (int r = 0; r < 16; ++r) {
                    float p0 = exp2f(sacc[0][r] - m_run);
                    float p1 = exp2f(sacc[1][r] - m_run);
                    sacc[0][r] = p0; sacc[1][r] = p1;
                    ps[r] = p0 + p1;
                }
                #pragma unroll
                for (int st = 8; st >= 1; st >>= 1)
                    #pragma unroll
                    for (int r2 = 0; r2 < 8; ++r2)
                        if (r2 < st) ps[r2] += ps[r2 + st];
                l_run += ps[0] + __shfl_xor(ps[0], 32);

                // ---- pack P^T: cvt_pk + permlane32_swap ----
                unsigned dw[16];
                #pragma unroll
                for (int u = 0; u < 16; ++u) {
                    float lo = sacc[u >> 3][(2 * u) & 15];
                    float hif = sacc[u >> 3][((2 * u) & 15) + 1];
                    asm("v_cvt_pk_bf16_f32 %0, %1, %2" : "=v"(dw[u]) : "v"(lo), "v"(hif));
                }

                // ---- O^T += V^T P^T ----
                __builtin_amdgcn_s_setprio(1);
                #pragma unroll
                for (int ks = 0; ks < 4; ++ks) {
                    unsigned a0 = dw[4 * ks],     b0 = dw[4 * ks + 2];
                    unsigned a1 = dw[4 * ks + 1], b1 = dw[4 * ks + 3];
                    asm("v_permlane32_swap_b32 %0, %1" : "+v"(a0), "+v"(b0));
                    asm("v_permlane32_swap_b32 %0, %1" : "+v"(a1), "+v"(b1));
                    union { unsigned u[4]; short8 v; } pb;
                    pb.u[0] = a0; pb.u[1] = a1; pb.u[2] = b0; pb.u[3] = b1;
                    #pragma unroll
                    for (int nb2 = 0; nb2 < 2; ++nb2) {
                        int row = 32 * nb2 + q31;
                        int lin = row * 128 + ks * 32 + hi * 16;
                        short8 av = *(const short8*)(Vbase + (lin ^ ((l & 7) << 4)));
                        acc_o[nb2] = __builtin_amdgcn_mfma_f32_32x32x16_bf16(av, pb.v, acc_o[nb2], 0, 0, 0);
                    }
                }
                __builtin_amdgcn_s_setprio(0);
            }
        }
        asm volatile("s_waitcnt vmcnt(0)" ::: "memory");
        __syncthreads();
    }

    // ---- merge halves via LDS: half B publishes, half A combines + writes out ----
    float* MB = (float*)&KV[0][0][0][0];
    float* slot = MB + (chunk * 64 + l) * 34;
    if (hf) {
        #pragma unroll
        for (int nb2 = 0; nb2 < 2; ++nb2)
            #pragma unroll
            for (int r = 0; r < 16; ++r) slot[nb2 * 16 + r] = acc_o[nb2][r];
        slot[32] = m_run; slot[33] = l_run;
    }
    __syncthreads();
    if (!hf) {
        float mB = slot[32], lB = slot[33];
        float m = fmaxf(m_run, mB);
        float cA = exp2f(m_run - m);
        float cB = (mB == -INFINITY) ? 0.f : exp2f(mB - m);
        float inv = 1.0f / (l_run * cA + lB * cB);
        float* ob = out + ((size_t)(b * T_LEN + qg)) * CDIM + h * DHEAD;
        #pragma unroll
        for (int nb2 = 0; nb2 < 2; ++nb2)
            #pragma unroll
            for (int r = 0; r < 16; ++r) {
                int dd = 32 * nb2 + (r & 3) + 8 * (r >> 2) + 4 * hi;
                ob[dd] = (acc_o[nb2][r] * cA + slot[nb2 * 16 + r] * cB) * inv;
            }
    }
}

extern "C" void kernel_launch(void* const* d_in, const int* in_sizes, int n_in,
                              void* d_out, int out_size, void* d_ws, size_t ws_size,
                              hipStream_t stream) {
    const float* x  = (const float*)d_in[0];
    const float* Wq = (const float*)d_in[1];
    const float* Wk = (const float*)d_in[2];
    const float* Wv = (const float*)d_in[3];
    float* out = (float*)d_out;

    unsigned short* xb = (unsigned short*)d_out;      // bf16 scratch in d_out (overwritten by attn)
    unsigned short* wb = xb + NX;
    unsigned short* qkv = (unsigned short*)d_ws;

    conv_bf16<<<dim3((NX / 8 + 3 * NW / 8) / 256), dim3(256), 0, stream>>>(x, Wq, Wk, Wv, xb);
    qkv_gemm_f<<<dim3(M_ROWS / 128, CDIM / 128, 3), dim3(256), 0, stream>>>(xb, wb, qkv);
    attn<<<dim3(512), dim3(512), 0, stream>>>(qkv, out);
}

// Round 15
// 99.171 us; speedup vs baseline: 1.1323x; 1.0297x over previous
//
#include <hip/hip_runtime.h>
#include <math.h>

typedef __attribute__((ext_vector_type(8))) short short8;
typedef __attribute__((ext_vector_type(4))) float f32x4;
typedef __attribute__((ext_vector_type(16))) float f32x16;

#define BDIM 2
#define T_LEN 2048
#define CDIM 1024
#define NH 16
#define DHEAD 64
#define M_ROWS (BDIM * T_LEN)            // 4096
#define NX (M_ROWS * CDIM)               // 4194304
#define NW (CDIM * CDIM)                 // 1048576

#define QSCL 0.045084220f                // C^-0.5 * log2(e), folded into Wq

__device__ inline unsigned short f2bf(float f) {
    union { float f; unsigned u; } v; v.f = f;
    unsigned r = v.u + 0x7fff + ((v.u >> 16) & 1);   // RNE
    return (unsigned short)(r >> 16);
}

__device__ __forceinline__ void gload16(const unsigned short* g, unsigned short* l) {
    __builtin_amdgcn_global_load_lds(
        (const __attribute__((address_space(1))) void*)g,
        (__attribute__((address_space(3))) void*)l, 16, 0, 0);
}

// ---------------- Kernel 0: fp32 -> bf16 convert (x, Wq*QSCL, Wk, Wv) ----------------
__global__ __launch_bounds__(256) void conv_bf16(
    const float* __restrict__ x, const float* __restrict__ wq,
    const float* __restrict__ wk, const float* __restrict__ wv,
    unsigned short* __restrict__ dst)
{
    int id = blockIdx.x * 256 + threadIdx.x;        // 16B-out chunk id
    const float* s;
    float scl = 1.0f;
    if (id < NX / 8) s = x + (size_t)id * 8;
    else {
        int r = id - NX / 8;
        int wsel = r >> 17;                          // NW/8 = 131072 = 2^17
        int off = r & 131071;
        const float* w = (wsel == 0) ? wq : (wsel == 1) ? wk : wv;
        if (wsel == 0) scl = QSCL;                   // pre-scale Q via Wq
        s = w + (size_t)off * 8;
    }
    float4 a = ((const float4*)s)[0];
    float4 b = ((const float4*)s)[1];
    union { unsigned short u[8]; short8 v; } o;
    o.u[0] = f2bf(a.x * scl); o.u[1] = f2bf(a.y * scl); o.u[2] = f2bf(a.z * scl); o.u[3] = f2bf(a.w * scl);
    o.u[4] = f2bf(b.x * scl); o.u[5] = f2bf(b.y * scl); o.u[6] = f2bf(b.z * scl); o.u[7] = f2bf(b.w * scl);
    *(short8*)(dst + (size_t)id * 8) = o.v;
}

// ---------------- Kernel 1: bf16 QKV GEMM, 128x128 tile, BK=64 (proven) ----------------
__global__ __launch_bounds__(256) void qkv_gemm_f(
    const unsigned short* __restrict__ xb, const unsigned short* __restrict__ wb,
    unsigned short* __restrict__ qkv)
{
    __shared__ unsigned short sh[17408];
    unsigned short* A = sh;
    unsigned short* Bt = sh + 8192;
    const int z = blockIdx.z;
    const int m0 = blockIdx.x * 128;
    const int n0 = blockIdx.y * 128;
    const int tid = threadIdx.x;
    const int l = tid & 63, w = tid >> 6;
    const int li = l & 15, g4 = l >> 4;
    const int wr = w >> 1, wc = w & 1;

    const unsigned short* wsrc = wb + (size_t)z * NW;
    f32x4 acc[4][4] = {};

    for (int k0 = 0; k0 < CDIM; k0 += 64) {
        __syncthreads();
        #pragma unroll
        for (int s = 0; s < 4; ++s) {
            int c = w * 256 + s * 64 + l;
            int row = c >> 3, wcol = c & 7;
            int sw = wcol ^ (row & 7);
            gload16(xb + (size_t)(m0 + row) * CDIM + k0 + sw * 8, A + (w * 256 + s * 64) * 8);
            gload16(wsrc + (size_t)(n0 + row) * CDIM + k0 + sw * 8, Bt + (w * 256 + s * 64) * 8);
        }
        asm volatile("s_waitcnt vmcnt(0)" ::: "memory");
        __syncthreads();
        __builtin_amdgcn_s_setprio(1);
        #pragma unroll
        for (int ks = 0; ks < 2; ++ks) {
            short8 af[4], bf[4];
            #pragma unroll
            for (int fm = 0; fm < 4; ++fm) {
                int row = wr * 64 + fm * 16 + li;
                int lin = row * 128 + ks * 64 + g4 * 16;
                af[fm] = *(const short8*)((const char*)A + (lin ^ ((row & 7) << 4)));
            }
            #pragma unroll
            for (int fn = 0; fn < 4; ++fn) {
                int row = wc * 64 + fn * 16 + li;
                int lin = row * 128 + ks * 64 + g4 * 16;
                bf[fn] = *(const short8*)((const char*)Bt + (lin ^ ((row & 7) << 4)));
            }
            #pragma unroll
            for (int fm = 0; fm < 4; ++fm)
                #pragma unroll
                for (int fn = 0; fn < 4; ++fn)
                    acc[fm][fn] = __builtin_amdgcn_mfma_f32_16x16x32_bf16(af[fm], bf[fn], acc[fm][fn], 0, 0, 0);
        }
        __builtin_amdgcn_s_setprio(0);
    }
    __syncthreads();

    if (z != 2) {
        unsigned short* outp = qkv + (size_t)z * NX;
        #pragma unroll
        for (int fm = 0; fm < 4; ++fm)
            #pragma unroll
            for (int fn = 0; fn < 4; ++fn)
                #pragma unroll
                for (int r = 0; r < 4; ++r) {
                    int m = m0 + wr * 64 + fm * 16 + g4 * 4 + r;
                    int n = n0 + wc * 64 + fn * 16 + li;
                    int b = m >> 11, t = m & 2047;
                    int h = n >> 6, dd = n & 63;
                    outp[((size_t)(b * NH + h) << 17) + ((size_t)t << 6) + dd] = f2bf(acc[fm][fn][r]);
                }
    } else {
        unsigned short (*T)[136] = (unsigned short(*)[136])sh;
        #pragma unroll
        for (int fm = 0; fm < 4; ++fm)
            #pragma unroll
            for (int fn = 0; fn < 4; ++fn)
                #pragma unroll
                for (int r = 0; r < 4; ++r) {
                    int ml = wr * 64 + fm * 16 + g4 * 4 + r;
                    int nl = wc * 64 + fn * 16 + li;
                    T[nl][ml] = f2bf(acc[fm][fn][r]);
                }
        __syncthreads();
        int b = m0 >> 11;
        int t0 = m0 & 2047;
        unsigned short* vt = qkv + 2 * (size_t)NX;
        #pragma unroll
        for (int s = 0; s < 8; ++s) {
            int row = tid >> 1;
            int col = ((tid & 1) * 8 + s) * 8;
            int ng = n0 + row;
            int h = ng >> 6, dd = ng & 63;
            *(short8*)(vt + ((size_t)(b * NH + h) * 64 + dd) * T_LEN + t0 + col)
                = *(const short8*)&T[row][col];
        }
    }
}

// ---------------- Kernel 2: causal flash attention, fused 128-wide softmax ----------------
// 8 waves, halves A/B split [0, bx+1) 128-tiles. Per staged tile: ONE fused step —
// QK 16 MFMA (4 indep chains), one 128-wide softmax, PV into split accumulators
// (sub0 -> acc_oA, sub1 -> acc_oB; merged in epilogue) -> 4 indep PV chains.
__global__ __launch_bounds__(512, 2) void attn(
    const unsigned short* __restrict__ qkv, float* __restrict__ out)
{
    // [half][dbuf][K=0/V=1][8192 shorts = 16KB] -> 128 KB
    __shared__ __align__(16) unsigned short KV[2][2][2][8192];

    const int id = blockIdx.x;
    const int half = id >> 8;
    const int rr = id & 255;
    const int tI = rr >> 5;                           // 0..7
    const int bx = half ? tI : (15 - tI);
    const int rb = rr & 31;
    const int bh = (rb & 7) * 4 + (rb >> 3);          // XCD spread
    const int b = bh >> 4, h = bh & 15;
    const int q0 = bx * 128;
    const int tid = threadIdx.x;
    const int l = tid & 63, w = tid >> 6;             // w: 0..7
    const int hf = w >> 2, chunk = w & 3;
    const int q31 = l & 31, hi = l >> 5;

    const unsigned short* qp = qkv + (size_t)bh * (T_LEN * DHEAD);
    const unsigned short* kp = qkv + (size_t)NX + (size_t)bh * (T_LEN * DHEAD);
    const unsigned short* vp = qkv + 2 * (size_t)NX + (size_t)bh * (T_LEN * DHEAD); // [dd][t]

    const int q0w = q0 + chunk * 32;
    const int qg = q0w + q31;

    short8 aq[4];
    #pragma unroll
    for (int ks = 0; ks < 4; ++ks)
        aq[ks] = *(const short8*)(qp + (size_t)qg * DHEAD + ks * 16 + hi * 8);

    float m_run = -INFINITY, l_run = 0.f;
    f32x16 acc_oA[2] = {};                            // sub0 accumulator
    f32x16 acc_oB[2] = {};                            // sub1 accumulator

    const int T128 = bx + 1;
    const int hA = (T128 + 1) >> 1;
    const int base = hf ? hA : 0;
    const int lim  = hf ? T128 : hA;
    const int nIt  = hA;
    const int myNt64 = 2 * bx + (chunk >> 1) + 1;     // causal 64-tile limit

    auto STAGE = [&](int j, int bf) {
        const int kv0 = j * 128;
        #pragma unroll
        for (int s = 0; s < 4; ++s) {
            int g = (chunk * 4 + s) * 64 + l;
            int krow = g >> 3, kc = g & 7;
            int ksw = kc ^ (krow & 7);
            gload16(kp + (size_t)(kv0 + krow) * DHEAD + ksw * 8, &KV[hf][bf][0][(chunk * 4 + s) * 512]);
            int sub = g >> 9, cs = g & 511;
            int vrow = cs >> 3, vc = cs & 7;
            int vsw = vc ^ (vrow & 7);
            gload16(vp + (size_t)vrow * T_LEN + kv0 + sub * 64 + vsw * 8, &KV[hf][bf][1][(chunk * 4 + s) * 512]);
        }
    };

    if (base < lim) STAGE(base, 0);
    asm volatile("s_waitcnt vmcnt(0)" ::: "memory");
    __syncthreads();

    for (int i = 0; i < nIt; ++i) {
        const int cur = i & 1;
        const int myJ = base + i;
        if (myJ + 1 < lim) STAGE(myJ + 1, cur ^ 1);

        if (myJ < lim && 2 * myJ < myNt64) {
            const char* Kbase = (const char*)&KV[hf][cur][0][0];
            const char* Vbase = (const char*)&KV[hf][cur][1][0];
            const int kv0 = myJ * 128;

            // ---- S^T over 128 kv rows: sacc[nb], nb = kv-group (32 rows each) ----
            f32x16 sacc[4] = {};
            __builtin_amdgcn_s_setprio(1);
            #pragma unroll
            for (int ks = 0; ks < 4; ++ks) {
                #pragma unroll
                for (int nb = 0; nb < 4; ++nb) {
                    int row = 32 * (nb & 1) + q31;
                    int lin = row * 128 + ks * 32 + hi * 16;
                    short8 ak = *(const short8*)(Kbase + (nb >> 1) * 8192 + (lin ^ ((l & 7) << 4)));
                    sacc[nb] = __builtin_amdgcn_mfma_f32_32x32x16_bf16(ak, aq[ks], sacc[nb], 0, 0, 0);
                }
            }
            __builtin_amdgcn_s_setprio(0);

            // ---- fused 128-wide online softmax (exp2 domain) ----
            const bool domask = (kv0 + 127 > q0w);
            if (domask) {
                #pragma unroll
                for (int nb = 0; nb < 4; ++nb)
                    #pragma unroll
                    for (int r = 0; r < 16; ++r) {
                        int kvg = kv0 + 32 * nb + (r & 3) + 8 * (r >> 2) + 4 * hi;
                        if (kvg > qg) sacc[nb][r] = -INFINITY;
                    }
            }
            float m16[16];
            #pragma unroll
            for (int r = 0; r < 16; ++r)
                m16[r] = fmaxf(fmaxf(sacc[0][r], sacc[1][r]), fmaxf(sacc[2][r], sacc[3][r]));
            #pragma unroll
            for (int st = 8; st >= 1; st >>= 1)
                #pragma unroll
                for (int r2 = 0; r2 < 8; ++r2)
                    if (r2 < st) m16[r2] = fmaxf(m16[r2], m16[r2 + st]);
            float mloc = fmaxf(m16[0], __shfl_xor(m16[0], 32));

            bool upd = mloc > m_run + 8.0f;           // defer-max
            if (__any(upd)) {
                float mn = fmaxf(m_run, mloc);
                float c = exp2f(m_run - mn);
                l_run *= c;
                #pragma unroll
                for (int nb2 = 0; nb2 < 2; ++nb2)
                    #pragma unroll
                    for (int r = 0; r < 16; ++r) {
                        acc_oA[nb2][r] *= c;
                        acc_oB[nb2][r] *= c;
                    }
                m_run = mn;
            }
            float ps[16];
            #pragma unroll
            for (int r = 0; r < 16; ++r) {
                float p0 = exp2f(sacc[0][r] - m_run);
                float p1 = exp2f(sacc[1][r] - m_run);
                float p2 = exp2f(sacc[2][r] - m_run);
                float p3 = exp2f(sacc[3][r] - m_run);
                sacc[0][r] = p0; sacc[1][r] = p1; sacc[2][r] = p2; sacc[3][r] = p3;
                ps[r] = (p0 + p1) + (p2 + p3);
            }
            #pragma unroll
            for (int st = 8; st >= 1; st >>= 1)
                #pragma unroll
                for (int r2 = 0; r2 < 8; ++r2)
                    if (r2 < st) ps[r2] += ps[r2 + st];
            l_run += ps[0] + __shfl_xor(ps[0], 32);

            // ---- pack P^T (per sub): cvt_pk + permlane32_swap; PV into split accs ----
            #pragma unroll
            for (int sub = 0; sub < 2; ++sub) {
                unsigned dw[16];
                #pragma unroll
                for (int u = 0; u < 16; ++u) {
                    float lo = sacc[2 * sub + (u >> 3)][(2 * u) & 15];
                    float hif = sacc[2 * sub + (u >> 3)][((2 * u) & 15) + 1];
                    asm("v_cvt_pk_bf16_f32 %0, %1, %2" : "=v"(dw[u]) : "v"(lo), "v"(hif));
                }
                f32x16* accp = sub ? acc_oB : acc_oA;
                __builtin_amdgcn_s_setprio(1);
                #pragma unroll
                for (int ks = 0; ks < 4; ++ks) {
                    unsigned a0 = dw[4 * ks],     b0 = dw[4 * ks + 2];
                    unsigned a1 = dw[4 * ks + 1], b1 = dw[4 * ks + 3];
                    asm("v_permlane32_swap_b32 %0, %1" : "+v"(a0), "+v"(b0));
                    asm("v_permlane32_swap_b32 %0, %1" : "+v"(a1), "+v"(b1));
                    union { unsigned u[4]; short8 v; } pb;
                    pb.u[0] = a0; pb.u[1] = a1; pb.u[2] = b0; pb.u[3] = b1;
                    #pragma unroll
                    for (int nb2 = 0; nb2 < 2; ++nb2) {
                        int row = 32 * nb2 + q31;
                        int lin = row * 128 + ks * 32 + hi * 16;
                        short8 av = *(const short8*)(Vbase + sub * 8192 + (lin ^ ((l & 7) << 4)));
                        accp[nb2] = __builtin_amdgcn_mfma_f32_32x32x16_bf16(av, pb.v, accp[nb2], 0, 0, 0);
                    }
                }
                __builtin_amdgcn_s_setprio(0);
            }
        }
        asm volatile("s_waitcnt vmcnt(0)" ::: "memory");
        __syncthreads();
    }

    // merge split accumulators
    f32x16 acc_o[2];
    #pragma unroll
    for (int nb2 = 0; nb2 < 2; ++nb2)
        #pragma unroll
        for (int r = 0; r < 16; ++r)
            acc_o[nb2][r] = acc_oA[nb2][r] + acc_oB[nb2][r];

    // ---- merge halves via LDS: half B publishes, half A combines + writes out ----
    float* MB = (float*)&KV[0][0][0][0];
    float* slot = MB + (chunk * 64 + l) * 34;
    if (hf) {
        #pragma unroll
        for (int nb2 = 0; nb2 < 2; ++nb2)
            #pragma unroll
            for (int r = 0; r < 16; ++r) slot[nb2 * 16 + r] = acc_o[nb2][r];
        slot[32] = m_run; slot[33] = l_run;
    }
    __syncthreads();
    if (!hf) {
        float mB = slot[32], lB = slot[33];
        float m = fmaxf(m_run, mB);
        float cA = exp2f(m_run - m);
        float cB = (mB == -INFINITY) ? 0.f : exp2f(mB - m);
        float inv = 1.0f / (l_run * cA + lB * cB);
        float* ob = out + ((size_t)(b * T_LEN + qg)) * CDIM + h * DHEAD;
        #pragma unroll
        for (int nb2 = 0; nb2 < 2; ++nb2)
            #pragma unroll
            for (int r = 0; r < 16; ++r) {
                int dd = 32 * nb2 + (r & 3) + 8 * (r >> 2) + 4 * hi;
                ob[dd] = (acc_o[nb2][r] * cA + slot[nb2 * 16 + r] * cB) * inv;
            }
    }
}

extern "C" void kernel_launch(void* const* d_in, const int* in_sizes, int n_in,
                              void* d_out, int out_size, void* d_ws, size_t ws_size,
                              hipStream_t stream) {
    const float* x  = (const float*)d_in[0];
    const float* Wq = (const float*)d_in[1];
    const float* Wk = (const float*)d_in[2];
    const float* Wv = (const float*)d_in[3];
    float* out = (float*)d_out;

    unsigned short* xb = (unsigned short*)d_out;      // bf16 scratch in d_out (overwritten by attn)
    unsigned short* wb = xb + NX;
    unsigned short* qkv = (unsigned short*)d_ws;

    conv_bf16<<<dim3((NX / 8 + 3 * NW / 8) / 256), dim3(256), 0, stream>>>(x, Wq, Wk, Wv, xb);
    qkv_gemm_f<<<dim3(M_ROWS / 128, CDIM / 128, 3), dim3(256), 0, stream>>>(xb, wb, qkv);
    attn<<<dim3(512), dim3(512), 0, stream>>>(qkv, out);
}